// Round 4
// baseline (182.810 us; speedup 1.0000x reference)
//
#include <hip/hip_runtime.h>

namespace {

constexpr int B_  = 2;
constexpr int N_  = 512;
constexpr int IN_ = 512;
constexpr int M_  = 300;   // MEM
constexpr int H_  = 64;    // HID
constexpr float SLOPE_ = 0.01f;

// ---- workspace layout (float offsets). No atomics; every buffer fully
// written by plain stores before read. ----
constexpr long OFF_CW1AI = 0;                         // 300 x 64
constexpr long OFF_CW1AJ = OFF_CW1AI + 300L * 64;
constexpr long OFF_BSI1  = OFF_CW1AJ + 300L * 64;     // 1 x 64
constexpr long OFF_BSJ1  = OFF_BSI1  + 64;
constexpr long OFF_H0    = OFF_BSJ1  + 64;            // 1024 x 300
constexpr long OFF_SI0   = OFF_H0    + 307200;        // 1024 x 64
constexpr long OFF_SJ0   = OFF_SI0   + 65536;
constexpr long OFF_H1    = OFF_SJ0   + 65536;         // 1024 x 300
constexpr long OFF_SI1   = OFF_H1    + 307200;
constexpr long OFF_SJ1   = OFF_SI1   + 65536;
constexpr long OFF_ZP0   = OFF_SJ1   + 65536;         // 256 (128/batch)
constexpr long OFF_ZP1   = OFF_ZP0   + 256;
constexpr long OFF_SLC   = OFF_ZP1   + 256;           // 8 x (1024 x 300)
// SLC holds f1 slices for layer 0 (consumed by D4), then is REUSED as the
// out slices for layer 1 (written by D5, consumed by D6). ~13 MB total.

__device__ __forceinline__ float4 f4add(float4 a, float4 b) {
    a.x += b.x; a.y += b.y; a.z += b.z; a.w += b.w; return a;
}

// ---------------------------------------------------------------------------
// One 32x64 GEMM tile (256 threads, 2x4 micro, TK=32, reg-prefetch staging).
//   C = scale * (sum_s A[s]) @ W + bias
// AFOLD: # of A partial buffers summed at load (stride afstride).
// Zp non-null: scale = 1/sum(Zp[zoff..zoff+128]), zoff = (row0>=512)?128:0
// (global softmax denominator of this tile's batch).
// ---------------------------------------------------------------------------
template<int AFOLD>
__device__ __forceinline__ void gemm_tile(
    const float* __restrict__ A, long afstride,
    const float* __restrict__ W, const float* __restrict__ bias,
    const float* __restrict__ Zp, float* __restrict__ C,
    int K, int lda, int Cc, int R, int local,
    float (*As)[38], float (*Ws)[64], float* zred)
{
    const int tx   = (Cc + 63) >> 6;
    const int row0 = (local / tx) * 32;
    const int col0 = (local % tx) * 64;

    const int t   = threadIdx.x;
    const int ar  = t >> 3;
    const int ak  = (t & 7) * 4;
    const int arow = min(row0 + ar, R - 1);
    const int wk  = t >> 4;
    const int wc  = (t & 15) * 4;
    const int tm0 = (t >> 4) * 2;
    const int tn0 = (t & 15) * 4;

    auto loadA = [&](int k0) -> float4 {
        const int k = k0 + ak;
        const long base = (long)arow * lda + k;
        float4 r = make_float4(0.f, 0.f, 0.f, 0.f);
        if (k + 3 < K) {
            #pragma unroll
            for (int s = 0; s < AFOLD; ++s)
                r = f4add(r, *(const float4*)(A + (long)s * afstride + base));
        } else {
            #pragma unroll
            for (int u = 0; u < 4; ++u)
                if (k + u < K) {
                    float v = 0.f;
                    #pragma unroll
                    for (int s = 0; s < AFOLD; ++s)
                        v += A[(long)s * afstride + base + u];
                    (&r.x)[u] = v;
                }
        }
        return r;
    };
    auto loadW = [&](int k0, int s) -> float4 {
        const int gk = k0 + wk + 16 * s;
        if (gk < K) {
            const int c = col0 + wc;
            if (c + 3 < Cc) return *(const float4*)(W + (long)gk * Cc + c);
            float tv[4];
            #pragma unroll
            for (int u = 0; u < 4; ++u)
                tv[u] = (c + u < Cc) ? W[(long)gk * Cc + c + u] : 0.0f;
            return make_float4(tv[0], tv[1], tv[2], tv[3]);
        }
        return make_float4(0.f, 0.f, 0.f, 0.f);
    };

    float acc[2][4] = {};
    float4 av  = loadA(0);
    float4 wv0 = loadW(0, 0);
    float4 wv1 = loadW(0, 1);

    for (int k0 = 0; k0 < K; k0 += 32) {
        As[ak + 0][ar] = av.x;
        As[ak + 1][ar] = av.y;
        As[ak + 2][ar] = av.z;
        As[ak + 3][ar] = av.w;
        *(float4*)&Ws[wk][wc]      = wv0;
        *(float4*)&Ws[wk + 16][wc] = wv1;
        __syncthreads();

        if (k0 + 32 < K) {                 // prefetch next slab behind compute
            av  = loadA(k0 + 32);
            wv0 = loadW(k0 + 32, 0);
            wv1 = loadW(k0 + 32, 1);
        }

        #pragma unroll
        for (int k = 0; k < 32; ++k) {
            const float a0 = As[k][tm0];
            const float a1 = As[k][tm0 + 1];
            const float4 w4 = *(const float4*)&Ws[k][tn0];
            acc[0][0] = fmaf(a0, w4.x, acc[0][0]);
            acc[0][1] = fmaf(a0, w4.y, acc[0][1]);
            acc[0][2] = fmaf(a0, w4.z, acc[0][2]);
            acc[0][3] = fmaf(a0, w4.w, acc[0][3]);
            acc[1][0] = fmaf(a1, w4.x, acc[1][0]);
            acc[1][1] = fmaf(a1, w4.y, acc[1][1]);
            acc[1][2] = fmaf(a1, w4.z, acc[1][2]);
            acc[1][3] = fmaf(a1, w4.w, acc[1][3]);
        }
        __syncthreads();
    }

    float scale = 1.0f;
    if (Zp != nullptr) {                   // softmax denom for this batch
        const int zoff = (row0 >= 512) ? 128 : 0;
        float v = (t < 128) ? Zp[zoff + t] : 0.f;
        #pragma unroll
        for (int off = 32; off > 0; off >>= 1)
            v += __shfl_down(v, off, 64);
        if ((t & 63) == 0) zred[t >> 6] = v;
        __syncthreads();
        scale = 1.0f / (zred[0] + zred[1] + zred[2] + zred[3]);
    }

    const int cbase = col0 + tn0;
    float bv[4] = {0.f, 0.f, 0.f, 0.f};
    if (bias != nullptr) {
        #pragma unroll
        for (int u = 0; u < 4; ++u)
            if (cbase + u < Cc) bv[u] = bias[cbase + u];
    }
    #pragma unroll
    for (int i = 0; i < 2; ++i) {
        const int r = row0 + tm0 + i;
        if (r < R) {
            if (cbase + 3 < Cc) {
                float4 o;
                o.x = fmaf(acc[i][0], scale, bv[0]);
                o.y = fmaf(acc[i][1], scale, bv[1]);
                o.z = fmaf(acc[i][2], scale, bv[2]);
                o.w = fmaf(acc[i][3], scale, bv[3]);
                *(float4*)(C + (long)r * Cc + cbase) = o;
            } else {
                #pragma unroll
                for (int u = 0; u < 4; ++u)
                    if (cbase + u < Cc)
                        C[(long)r * Cc + cbase + u] = fmaf(acc[i][u], scale, bv[u]);
            }
        }
    }
}

struct JobsK {
    const float* A[5]; long afstride[5];
    const float* W[5]; const float* bias[5]; const float* Zp[5];
    float* C[5];
    int K[5]; int lda[5]; int Cc[5]; int R[5];
    int off[5]; int njobs;
};

template<int AFOLD>
__global__ __launch_bounds__(256)
void gemm_jobs(JobsK jb)
{
    __shared__ __align__(16) float As[32][38];
    __shared__ __align__(16) float Ws[32][64];
    __shared__ float zred[4];

    const int bid = blockIdx.x;
    int j = jb.njobs - 1;
    while (j > 0 && bid < jb.off[j]) --j;
    const int local = bid - jb.off[j];

    gemm_tile<AFOLD>(jb.A[j], jb.afstride[j], jb.W[j], jb.bias[j], jb.Zp[j],
                     jb.C[j], jb.K[j], jb.lda[j], jb.Cc[j], jb.R[j],
                     local, As, Ws, zred);
}

// ---------------------------------------------------------------------------
// Fused attention + PV (flash-style): block = (batch, i-tile 32 rows,
// j-slice 64 cols). Computes e -> p (LDS only, never to HBM), Zpart, then
// p @ h[j-slice, 0:300] -> unnormalized output slice js. Consumer folds the
// 8 slices and applies 1/Z (both linear in p).
// ---------------------------------------------------------------------------
__global__ __launch_bounds__(256)
void attn_pv(const float* __restrict__ si, const float* __restrict__ sj,
             const float* __restrict__ adj, const float* __restrict__ a2w,
             const float* __restrict__ a2b, const float* __restrict__ h,
             float* __restrict__ slc, float* __restrict__ Zpart)
{
    __shared__ __align__(16) float Si[32][68];
    __shared__ __align__(16) float Sj[64][68];
    __shared__ __align__(16) float Pt[64][36];   // p transposed [j][i]
    __shared__ __align__(16) float Hs[64][68];
    __shared__ float red[4];

    const int bid = blockIdx.x;          // 256 blocks: b*128 + it*8 + js
    const int b   = bid >> 7;
    const int rr_ = bid & 127;
    const int it  = rr_ >> 3;
    const int js  = rr_ & 7;
    const int i0  = it * 32;
    const int j0  = js * 64;
    const int t   = threadIdx.x;

    {   // stage si tile (32 x 64)
        const int r  = t >> 3;
        const int hc = (t & 7) * 8;
        const float* gi = si + ((long)(b * N_ + i0 + r)) * H_ + hc;
        *(float4*)&Si[r][hc]     = *(const float4*)(gi);
        *(float4*)&Si[r][hc + 4] = *(const float4*)(gi + 4);
    }
    {   // stage sj slice (64 x 64)
        const int r  = t >> 2;
        const int hc = (t & 3) * 16;
        const float* gj = sj + ((long)(b * N_ + j0 + r)) * H_ + hc;
        *(float4*)&Sj[r][hc]      = *(const float4*)(gj);
        *(float4*)&Sj[r][hc + 4]  = *(const float4*)(gj + 4);
        *(float4*)&Sj[r][hc + 8]  = *(const float4*)(gj + 8);
        *(float4*)&Sj[r][hc + 12] = *(const float4*)(gj + 12);
    }
    __syncthreads();

    const int i  = t >> 3;               // 0..31
    const int jl = t & 7;                // j = jl + 8u, u = 0..7

    float e[8] = {0.f, 0.f, 0.f, 0.f, 0.f, 0.f, 0.f, 0.f};
    #pragma unroll
    for (int h0 = 0; h0 < H_; h0 += 4) {
        const float4 a4 = *(const float4*)&Si[i][h0];
        const float w0v = a2w[h0 + 0];
        const float w1v = a2w[h0 + 1];
        const float w2v = a2w[h0 + 2];
        const float w3v = a2w[h0 + 3];
        #pragma unroll
        for (int u = 0; u < 8; ++u) {
            const float4 b4 = *(const float4*)&Sj[jl + 8 * u][h0];
            e[u] = fmaf(fmaxf(a4.x + b4.x, 0.f), w0v, e[u]);
            e[u] = fmaf(fmaxf(a4.y + b4.y, 0.f), w1v, e[u]);
            e[u] = fmaf(fmaxf(a4.z + b4.z, 0.f), w2v, e[u]);
            e[u] = fmaf(fmaxf(a4.w + b4.w, 0.f), w3v, e[u]);
        }
    }

    const float a2bv = a2b[0];
    const long rowbase = ((long)(b * N_ + i0 + i)) * N_ + j0 + jl;
    float lsum = 0.f;
    #pragma unroll
    for (int u = 0; u < 8; ++u) {
        float ev = e[u] + a2bv;
        ev = (ev >= 0.f) ? ev : SLOPE_ * ev;
        const float m  = adj[rowbase + 8 * u];
        const float pv = m * __expf(ev);
        Pt[jl + 8 * u][i] = pv;          // [64][36] pad: conflict-light
        lsum += pv;
    }

    #pragma unroll
    for (int off = 32; off > 0; off >>= 1)
        lsum += __shfl_down(lsum, off, 64);
    if ((t & 63) == 0) red[t >> 6] = lsum;
    __syncthreads();                      // also publishes Pt
    if (t == 0)
        Zpart[b * 128 + it * 8 + js] = red[0] + red[1] + red[2] + red[3];

    // ---- PV: (32 x 64 p) @ (64 x 300 h-slice), 5 col chunks of 64 ----
    const int tm0 = (t >> 4) * 2;
    const int tn0 = (t & 15) * 4;
    float* dst = slc + (long)js * 307200;

    for (int cc = 0; cc < 5; ++cc) {
        const int c0 = cc * 64;
        {   // stage h[j0..j0+63][c0..c0+63]
            const int r  = t >> 2;
            const int hc = (t & 3) * 16;
            const float* gh = h + ((long)(b * N_ + j0 + r)) * M_ + c0 + hc;
            if (c0 + hc + 15 < M_) {
                *(float4*)&Hs[r][hc]      = *(const float4*)(gh);
                *(float4*)&Hs[r][hc + 4]  = *(const float4*)(gh + 4);
                *(float4*)&Hs[r][hc + 8]  = *(const float4*)(gh + 8);
                *(float4*)&Hs[r][hc + 12] = *(const float4*)(gh + 12);
            } else {
                #pragma unroll
                for (int u = 0; u < 16; ++u)
                    Hs[r][hc + u] = (c0 + hc + u < M_) ? gh[u] : 0.f;
            }
        }
        __syncthreads();

        float acc[2][4] = {};
        #pragma unroll
        for (int k = 0; k < 64; ++k) {
            const float a0 = Pt[k][tm0];
            const float a1 = Pt[k][tm0 + 1];
            const float4 w4 = *(const float4*)&Hs[k][tn0];
            acc[0][0] = fmaf(a0, w4.x, acc[0][0]);
            acc[0][1] = fmaf(a0, w4.y, acc[0][1]);
            acc[0][2] = fmaf(a0, w4.z, acc[0][2]);
            acc[0][3] = fmaf(a0, w4.w, acc[0][3]);
            acc[1][0] = fmaf(a1, w4.x, acc[1][0]);
            acc[1][1] = fmaf(a1, w4.y, acc[1][1]);
            acc[1][2] = fmaf(a1, w4.z, acc[1][2]);
            acc[1][3] = fmaf(a1, w4.w, acc[1][3]);
        }

        const int cb = c0 + tn0;
        #pragma unroll
        for (int ii = 0; ii < 2; ++ii) {
            const long r = (long)(b * N_ + i0 + tm0 + ii);
            if (cb + 3 < M_) {
                *(float4*)(dst + r * M_ + cb) =
                    make_float4(acc[ii][0], acc[ii][1], acc[ii][2], acc[ii][3]);
            } else {
                #pragma unroll
                for (int u = 0; u < 4; ++u)
                    if (cb + u < M_) dst[r * M_ + cb + u] = acc[ii][u];
            }
        }
        __syncthreads();                  // before Hs overwrite
    }
}

// ---------------------------------------------------------------------------
// Finalize: out = (sum of 8 slices) / Z1[batch].  300 blocks x 256 thr,
// one float4 per thread (rows of 300 floats = 75 float4, no straddle).
// ---------------------------------------------------------------------------
__global__ __launch_bounds__(256)
void finalize(const float* __restrict__ slc, const float* __restrict__ Zp,
              float* __restrict__ out)
{
    __shared__ float red[4];
    const int t = threadIdx.x;

    float v = Zp[t];                      // 256 entries; waves 0,1 = batch 0
    #pragma unroll
    for (int off = 32; off > 0; off >>= 1)
        v += __shfl_down(v, off, 64);
    if ((t & 63) == 0) red[t >> 6] = v;
    __syncthreads();
    const float s0 = 1.0f / (red[0] + red[1]);
    const float s1 = 1.0f / (red[2] + red[3]);

    const int idx = blockIdx.x * 256 + t;             // < 76800
    const float4* src = (const float4*)slc;
    float4 a = src[idx];
    #pragma unroll
    for (int s = 1; s < 8; ++s) a = f4add(a, src[idx + s * 76800]);
    const float sc = (idx < 38400) ? s0 : s1;         // row = idx/75
    a.x *= sc; a.y *= sc; a.z *= sc; a.w *= sc;
    ((float4*)out)[idx] = a;
}

} // namespace

extern "C" void kernel_launch(void* const* d_in, const int* in_sizes, int n_in,
                              void* d_out, int out_size, void* d_ws, size_t ws_size,
                              hipStream_t stream)
{
    (void)in_sizes; (void)n_in; (void)out_size; (void)ws_size;
    const float* feature = (const float*)d_in[0];
    const float* adj     = (const float*)d_in[1];
    const float* w0      = (const float*)d_in[2];
    const float* b0      = (const float*)d_in[3];
    const float* w1      = (const float*)d_in[4];
    const float* b1      = (const float*)d_in[5];
    const float* a1w     = (const float*)d_in[6];   // (600, 64) row-major
    const float* a1b     = (const float*)d_in[7];
    const float* a2w     = (const float*)d_in[8];
    const float* a2b     = (const float*)d_in[9];
    float* out = (float*)d_out;
    float* ws  = (float*)d_ws;

    float* cW1Ai = ws + OFF_CW1AI;
    float* cW1Aj = ws + OFF_CW1AJ;
    float* bsi1  = ws + OFF_BSI1;
    float* bsj1  = ws + OFF_BSJ1;
    float* h0    = ws + OFF_H0;
    float* si0   = ws + OFF_SI0;
    float* sj0   = ws + OFF_SJ0;
    float* h1    = ws + OFF_H1;
    float* si1   = ws + OFF_SI1;
    float* sj1   = ws + OFF_SJ1;
    float* Zp0   = ws + OFF_ZP0;
    float* Zp1   = ws + OFF_ZP1;
    float* slc   = ws + OFF_SLC;   // f1 slices (D3/D4), then out slices (D5/D6)

    const float* Ai = a1w;                    // top half (300 x 64)
    const float* Aj = a1w + (long)M_ * H_;    // bottom half

    auto set_job = [](JobsK& jb, int j, const float* A, long afstride,
                      const float* W, const float* bias, const float* Zp,
                      float* C, int K, int lda, int Cc, int R, int& tiles) {
        jb.A[j] = A; jb.afstride[j] = afstride;
        jb.W[j] = W; jb.bias[j] = bias; jb.Zp[j] = Zp; jb.C[j] = C;
        jb.K[j] = K; jb.lda[j] = lda; jb.Cc[j] = Cc; jb.R[j] = R;
        jb.off[j] = tiles;
        tiles += ((R + 31) / 32) * ((Cc + 63) / 64);
    };

    // ---- D1: h0 = feature@w0+b0  |  layer-1 fused weights (182 blocks) ----
    {
        JobsK jb; int tiles = 0;
        set_job(jb, 0, feature, 0, w0, b0,   nullptr, h0,    IN_, IN_, M_, 1024, tiles);
        set_job(jb, 1, w1,      0, Ai, nullptr, nullptr, cW1Ai, M_, M_, H_, M_, tiles);
        set_job(jb, 2, w1,      0, Aj, nullptr, nullptr, cW1Aj, M_, M_, H_, M_, tiles);
        set_job(jb, 3, b1,      0, Ai, nullptr, nullptr, bsi1,  M_, M_, H_, 1,  tiles);
        set_job(jb, 4, b1,      0, Aj, a1b,     nullptr, bsj1,  M_, M_, H_, 1,  tiles);
        jb.njobs = 5;
        gemm_jobs<1><<<dim3(tiles), dim3(256), 0, stream>>>(jb);
    }

    // ---- D2: si0 = h0@Ai, sj0 = h0@Aj + a1b (64 blocks) ----
    {
        JobsK jb; int tiles = 0;
        set_job(jb, 0, h0, 0, Ai, nullptr, nullptr, si0, M_, M_, H_, 1024, tiles);
        set_job(jb, 1, h0, 0, Aj, a1b,     nullptr, sj0, M_, M_, H_, 1024, tiles);
        jb.njobs = 2;
        gemm_jobs<1><<<dim3(tiles), dim3(256), 0, stream>>>(jb);
    }

    // ---- D3: fused attn0 + PV0 -> f1 slices (unnorm) + Zp0 (256 blocks) ----
    attn_pv<<<dim3(256), dim3(256), 0, stream>>>(
        si0, sj0, adj, a2w, a2b, h0, slc, Zp0);

    // ---- D4: h1/si1/sj1 = (1/Z0)*(sum 8 f1 slices)@{w1,cW1Ai,cW1Aj}+bias ----
    {
        JobsK jb; int tiles = 0;
        set_job(jb, 0, slc, 307200, w1,    b1,   Zp0, h1,  M_, M_, M_, 1024, tiles);
        set_job(jb, 1, slc, 307200, cW1Ai, bsi1, Zp0, si1, M_, M_, H_, 1024, tiles);
        set_job(jb, 2, slc, 307200, cW1Aj, bsj1, Zp0, sj1, M_, M_, H_, 1024, tiles);
        jb.njobs = 3;
        gemm_jobs<8><<<dim3(tiles), dim3(256), 0, stream>>>(jb);  // 224 blocks
    }

    // ---- D5: fused attn1 + PV1 -> out slices (unnorm, reuses slc) + Zp1 ----
    attn_pv<<<dim3(256), dim3(256), 0, stream>>>(
        si1, sj1, adj, a2w, a2b, h1, slc, Zp1);

    // ---- D6: out = (sum 8 slices)/Z1 (300 blocks) ----
    finalize<<<dim3(300), dim3(256), 0, stream>>>(slc, Zp1, out);
}